// Round 8
// baseline (239.630 us; speedup 1.0000x reference)
//
#include <hip/hip_runtime.h>
#include <hip/hip_bf16.h>
#include <stdint.h>

// Problem sizes (compile-time)
static constexpr int BATCH = 32768;
static constexpr int DIN   = 512;
static constexpr int DHID  = 1024;
static constexpr int DOUT  = 2048;

typedef __bf16 bf16x8 __attribute__((ext_vector_type(8)));
typedef float  f32x4  __attribute__((ext_vector_type(4)));

// fp32 -> bf16 round-to-nearest-even
__device__ __forceinline__ unsigned short f2bf(float f) {
    unsigned int u = __float_as_uint(f);
    u += 0x7FFFu + ((u >> 16) & 1u);
    return (unsigned short)(u >> 16);
}

// async global->LDS, 16B per lane. LDS dest = WAVE-uniform base + 16*(lane&63).
__device__ __forceinline__ void gload_lds16(const void* g, void* l) {
    __builtin_amdgcn_global_load_lds((__attribute__((address_space(1))) void*)g,
                                     (__attribute__((address_space(3))) void*)l,
                                     16, 0, 0);
}

// ===========================================================================
// scores = x @ W^T + b' (algebraic fusion; absmax 0.03125 measured)
// r22: LDS-TRAFFIC ELIMINATION. r19 was LDS-BW-bound: 88 KB/slot (64 read +
// 24 gload-write) / 85 B/cyc = 1060 cyc > MFMA 620 -> every schedule tweak
// (r5 barrier removal, r7 2-block) was null/negative. Fix:
//  (1) B direct from L2 to registers (W is 2 MB, XCD-L2-resident): lane
//      pattern col=r, k-octet=q -> 4 lanes per 64B line. -40 KB/slot LDS.
//  (2) A (tile-invariant in the N-walk) staged ONCE: BM=128 -> 128 KB LDS,
//      16 K32-units; staged r19-style across tile 0's 16 phases (VMC(6)
//      ledger + per-phase BAR), then tiles 1..7 are stage-free and
//      BARRIER-FREE (LDS read-only -> no WAR/RAW; waves free-run).
// LDS/slot: 88 -> 32 KB (A-frag reads, ~385 cyc) < MFMA 620 -> MFMA-bound.
// B prefetched 1 phase ahead into E/O register sets (+32 VGPR; total ~160,
// far from the 256 cliff that killed r16/r17/r20).
// Ledger: prologue [B0(4),A0,A1,A2] VMC(2); tile0 p0-12 VMC(6) (stage p+3),
// p13-15 VMC(4); steady [B(s)4,B(s+1)4] VMC(4); last phase VMC(0).
// Block = 128 rows x all 2048 cols -> direct out write (no reduce kernel).
// ===========================================================================

// ---------------------------------------------------------------------------
// prep: one dispatch, region-decoded by blockIdx.x (unchanged)
// ---------------------------------------------------------------------------
__global__ __launch_bounds__(256) void prep_kernel(
    const float* __restrict__ w1, const float4* __restrict__ w2f,
    const float4* __restrict__ xf, const float* __restrict__ b1,
    const float* __restrict__ b2,
    unsigned short* __restrict__ w1t, ushort4* __restrict__ w2b,
    ushort4* __restrict__ xb, float* __restrict__ bp) {
    const int blk = blockIdx.x;
    const int t   = threadIdx.x;
    if (blk < 512) {
        __shared__ float tile[32][33];
        const int tileI = blk & 15;
        const int tileH = blk >> 4;
        const int iBase = tileI * 32, hBase = tileH * 32;
        const int col = t & 31, rowq = t >> 5;
#pragma unroll
        for (int p = 0; p < 4; ++p) {
            const int row = p * 8 + rowq;
            tile[row][col] = w1[(size_t)(hBase + row) * DIN + iBase + col];
        }
        __syncthreads();
#pragma unroll
        for (int p = 0; p < 4; ++p) {
            const int row = p * 8 + rowq;
            w1t[(size_t)(iBase + row) * DHID + hBase + col] = f2bf(tile[col][row]);
        }
    } else if (blk < 2560) {
        __shared__ float wsum[4];
        const int o = blk - 512;
        const size_t g = (size_t)o * 256 + t;
        float4 v = w2f[g];
        ushort4 ob;
        ob.x = f2bf(v.x); ob.y = f2bf(v.y); ob.z = f2bf(v.z); ob.w = f2bf(v.w);
        w2b[g] = ob;
        float4 bv = ((const float4*)b1)[t];
        float s = v.x * bv.x + v.y * bv.y + v.z * bv.z + v.w * bv.w;
#pragma unroll
        for (int off = 1; off < 64; off <<= 1) s += __shfl_xor(s, off);
        if ((t & 63) == 0) wsum[t >> 6] = s;
        __syncthreads();
        if (t == 0) bp[o] = wsum[0] + wsum[1] + wsum[2] + wsum[3] + b2[o];
    } else {
        // 4096 blocks x 256 thr x 4 float4 = 4194304 float4 groups
        const size_t base = (size_t)(blk - 2560) * 1024 + t;
#pragma unroll
        for (int i = 0; i < 4; ++i) {
            float4 v = xf[base + i * 256];
            ushort4 o;
            o.x = f2bf(v.x); o.y = f2bf(v.y); o.z = f2bf(v.z); o.w = f2bf(v.w);
            xb[base + i * 256] = o;
        }
    }
}

// ---------------------------------------------------------------------------
// gemmW: W[o,i] = sum_h w2b[o,h] * w1t[i,h]. (unchanged)
// ---------------------------------------------------------------------------
__global__ __launch_bounds__(256) void gemmW_kernel(
    const unsigned short* __restrict__ A,
    const unsigned short* __restrict__ Bw,
    unsigned short* __restrict__ W) {
    constexpr int K = DHID;
    __shared__ __align__(16) unsigned short sA[64 * 128];
    __shared__ __align__(16) unsigned short sB[64 * 128];

    const int tid  = threadIdx.x;
    const int lane = tid & 63;
    const int wid  = tid >> 6;
    const int wr = wid >> 1, wc = wid & 1;
    const int r = lane & 15, q = lane >> 4;
    const int blockN = blockIdx.x * 64;
    const int blockM = blockIdx.y * 64;

    const int chKey = (tid & 15) ^ ((tid >> 4) & 15);
    const size_t aBase = (size_t)(blockM + (tid >> 4)) * K + chKey * 8;
    const size_t bBase = (size_t)(blockN + (tid >> 4)) * K + chKey * 8;

    f32x4 acc[2][2];
#pragma unroll
    for (int mt = 0; mt < 2; ++mt)
#pragma unroll
        for (int nt = 0; nt < 2; ++nt) { f32x4 z = {0.f, 0.f, 0.f, 0.f}; acc[mt][nt] = z; }

    for (int k0 = 0; k0 < K; k0 += 128) {
#pragma unroll
        for (int j = 0; j < 4; ++j) {
            gload_lds16(A  + aBase + (size_t)j * 16 * K + k0, sA + j * 2048 + wid * 512);
            gload_lds16(Bw + bBase + (size_t)j * 16 * K + k0, sB + j * 2048 + wid * 512);
        }
        __syncthreads();
#pragma unroll
        for (int ks = 0; ks < 4; ++ks) {
            const int ch = ((ks << 2) + q) ^ r;
            bf16x8 af[2], bf[2];
#pragma unroll
            for (int mt = 0; mt < 2; ++mt) af[mt] = *(const bf16x8*)&sA[(wr * 32 + mt * 16 + r) * 128 + ch * 8];
#pragma unroll
            for (int nt = 0; nt < 2; ++nt) bf[nt] = *(const bf16x8*)&sB[(wc * 32 + nt * 16 + r) * 128 + ch * 8];
#pragma unroll
            for (int mt = 0; mt < 2; ++mt)
#pragma unroll
                for (int nt = 0; nt < 2; ++nt)
                    acc[mt][nt] = __builtin_amdgcn_mfma_f32_16x16x32_bf16(af[mt], bf[nt], acc[mt][nt], 0, 0, 0);
        }
        __syncthreads();
    }

#pragma unroll
    for (int mt = 0; mt < 2; ++mt) {
        const int row0 = blockM + wr * 32 + mt * 16 + q * 4;
#pragma unroll
        for (int nt = 0; nt < 2; ++nt) {
            const int col = blockN + wc * 32 + nt * 16 + r;
#pragma unroll
            for (int reg = 0; reg < 4; ++reg)
                W[(size_t)(row0 + reg) * DIN + col] = f2bf(acc[mt][nt][reg]);
        }
    }
}

// ---------------------------------------------------------------------------
// gemmS r22: 256 blocks x 512 thr (8 waves = 2M x 4N), BM=128, walks 8
// N-tiles of 256. A in LDS once (16 units x 8KB, K32 each); B direct L2->reg.
// LDS (shorts): A unit s at s*4096 [0,65536); bias 2048 f32 at 65536. 136 KB.
// A unit layout: 128 rows x 32k; chunk c holds global chunk c^((row>>1)&3)
// (pre-swizzled source, linear dest); frag read chunk q^((r>>1)&3).
// B frag (16x16x32 B-operand): lane = B[col=r][k=q*8..q*8+7] -> 16B deref at
// W[(col)*512 + s*32 + q*8]; 4 lanes (q) share one 64B line.
// ---------------------------------------------------------------------------
__global__ __launch_bounds__(512, 2) void gemmS_kernel(
    const unsigned short* __restrict__ A,   // xb bf16 [BATCH, DIN]
    const unsigned short* __restrict__ Bw,  // W bf16 [2048, 512]
    const float* __restrict__ bp,           // b' [DOUT]
    float* __restrict__ out) {              // [BATCH]
    __shared__ __align__(16) unsigned short lds[69632];  // 136 KB

    const int tid  = threadIdx.x;            // 0..511
    const int lane = tid & 63;
    const int wid  = tid >> 6;               // 0..7
    const int wr   = wid >> 2;               // 0..1 (M half, 64 rows)
    const int wc   = wid & 3;                // 0..3 (N quarter, 64 cols)
    const int r    = lane & 15, q = lane >> 4;

    // 256 blocks = 8 xcd x 32; block owns 128 rows, all 2048 cols.
    const int b    = blockIdx.x;
    const int xcd  = b & 7;
    const int j    = b >> 3;                 // 0..31
    const int blockM = (xcd * 32 + j) * 128;

    // A staging address (pre-swizzled global source); 1 gload per unit.
    const int sRow = tid >> 2;               // 0..127
    const int swz  = (tid & 3) ^ ((tid >> 3) & 3);
    const unsigned short* aSrc = A + (size_t)(blockM + sRow) * DIN + swz * 8;
    float* biasLds = (float*)(lds + 65536);

#define STAGE_A(s) \
    gload_lds16(aSrc + (s) * 32, lds + (s) * 4096 + wid * 512)

    // A fragment read base (swizzled chunk)
    const int fOff = (q ^ ((r >> 1) & 3)) * 8;
    const unsigned short* ldsAf = lds + (wr * 64 + r) * 32 + fOff;

    // B per-lane pointers, one per nt (advanced by 131072 shorts per tile).
    const unsigned short* bT0 = Bw + (size_t)(wc * 64 + 0 * 16 + r) * DIN + q * 8;
    const unsigned short* bT1 = Bw + (size_t)(wc * 64 + 1 * 16 + r) * DIN + q * 8;
    const unsigned short* bT2 = Bw + (size_t)(wc * 64 + 2 * 16 + r) * DIN + q * 8;
    const unsigned short* bT3 = Bw + (size_t)(wc * 64 + 3 * 16 + r) * DIN + q * 8;

    f32x4 acc[4][4];
#pragma unroll
    for (int mt = 0; mt < 4; ++mt)
#pragma unroll
        for (int nt = 0; nt < 4; ++nt) { f32x4 z = {0.f, 0.f, 0.f, 0.f}; acc[mt][nt] = z; }
    float mx[4][4];
#pragma unroll
    for (int mt = 0; mt < 4; ++mt)
#pragma unroll
        for (int rg = 0; rg < 4; ++rg) mx[mt][rg] = -INFINITY;
    bf16x8 af[4], bfrE[4], bfrO[4];
    float bvc[4];

#define RD_A(s) do {                                                            \
    const unsigned short* pa_ = ldsAf + (s) * 4096;                             \
    af[0] = *(const bf16x8*)(pa_);                                              \
    af[1] = *(const bf16x8*)(pa_ + 512);                                        \
    af[2] = *(const bf16x8*)(pa_ + 1024);                                       \
    af[3] = *(const bf16x8*)(pa_ + 1536);                                       \
} while (0)
// soff = slot*32 (+131072 for next tile)
#define BPREF_E(soff) do {                                                      \
    bfrE[0] = *(const bf16x8*)(bT0 + (soff));                                   \
    bfrE[1] = *(const bf16x8*)(bT1 + (soff));                                   \
    bfrE[2] = *(const bf16x8*)(bT2 + (soff));                                   \
    bfrE[3] = *(const bf16x8*)(bT3 + (soff));                                   \
} while (0)
#define BPREF_O(soff) do {                                                      \
    bfrO[0] = *(const bf16x8*)(bT0 + (soff));                                   \
    bfrO[1] = *(const bf16x8*)(bT1 + (soff));                                   \
    bfrO[2] = *(const bf16x8*)(bT2 + (soff));                                   \
    bfrO[3] = *(const bf16x8*)(bT3 + (soff));                                   \
} while (0)
#define MM_E() do {                                                             \
    __builtin_amdgcn_s_setprio(1);                                              \
    _Pragma("unroll") for (int m_ = 0; m_ < 4; ++m_)                            \
    _Pragma("unroll") for (int n_ = 0; n_ < 4; ++n_)                            \
        acc[m_][n_] = __builtin_amdgcn_mfma_f32_16x16x32_bf16(                  \
            af[m_], bfrE[n_], acc[m_][n_], 0, 0, 0);                            \
    __builtin_amdgcn_s_setprio(0);                                              \
} while (0)
#define MM_O() do {                                                             \
    __builtin_amdgcn_s_setprio(1);                                              \
    _Pragma("unroll") for (int m_ = 0; m_ < 4; ++m_)                            \
    _Pragma("unroll") for (int n_ = 0; n_ < 4; ++n_)                            \
        acc[m_][n_] = __builtin_amdgcn_mfma_f32_16x16x32_bf16(                  \
            af[m_], bfrO[n_], acc[m_][n_], 0, 0, 0);                            \
    __builtin_amdgcn_s_setprio(0);                                              \
} while (0)
#define BAR()   __builtin_amdgcn_s_barrier()
#define SB0()   __builtin_amdgcn_sched_barrier(0)
#define LGKM0() asm volatile("s_waitcnt lgkmcnt(0)" ::: "memory")
#define VMC(n)  asm volatile("s_waitcnt vmcnt(" #n ")" ::: "memory")

#define FOLD() do {                                                             \
    _Pragma("unroll") for (int mt_ = 0; mt_ < 4; ++mt_)                         \
    _Pragma("unroll") for (int rg_ = 0; rg_ < 4; ++rg_) {                       \
        float v_ = fmaxf(fmaxf(acc[mt_][0][rg_] + bvc[0],                       \
                               acc[mt_][1][rg_] + bvc[1]),                      \
                         fmaxf(acc[mt_][2][rg_] + bvc[2],                       \
                               acc[mt_][3][rg_] + bvc[3]));                     \
        mx[mt_][rg_] = fmaxf(mx[mt_][rg_], v_);                                 \
    }                                                                           \
} while (0)
#define ACC_ZERO() do {                                                         \
    _Pragma("unroll") for (int mt_ = 0; mt_ < 4; ++mt_)                         \
    _Pragma("unroll") for (int nt_ = 0; nt_ < 4; ++nt_) {                       \
        f32x4 z_ = {0.f, 0.f, 0.f, 0.f}; acc[mt_][nt_] = z_;                    \
    }                                                                           \
} while (0)

    // Bias -> LDS (compiler drains its load before the ds_write; ledger clean).
    {
        float4 bb = ((const float4*)bp)[tid];      // 512 x 16B = 8 KB = all of b'
        ((float4*)biasLds)[tid] = bb;
    }
    LGKM0();

    // Prologue: B(0) first, then A units 0,1,2. VMC(2) = oldest 5 (B0+A0).
    BPREF_E(0);
    STAGE_A(0); STAGE_A(1); STAGE_A(2);
    VMC(2);
    BAR();

    // bias for tile 0
#pragma unroll
    for (int nt = 0; nt < 4; ++nt) bvc[nt] = biasLds[wc * 64 + nt * 16 + r];

    // ---- tile 0: stage A units 3..15 across phases 0..12, with barriers ----
    // phase s (0..12): RD_A(s) | BPREF(s+1) | STAGE_A(s+3) | VMC(6) | MM | BAR
#define PH0S(s, PREF, MM_) do {                                                 \
    RD_A(s); PREF((s + 1) * 32); STAGE_A((s) + 3);                              \
    VMC(6); LGKM0(); SB0(); MM_(); BAR();                                       \
} while (0)
    PH0S(0,  BPREF_O, MM_E);
    PH0S(1,  BPREF_E, MM_O);
    PH0S(2,  BPREF_O, MM_E);
    PH0S(3,  BPREF_E, MM_O);
    PH0S(4,  BPREF_O, MM_E);
    PH0S(5,  BPREF_E, MM_O);
    PH0S(6,  BPREF_O, MM_E);
    PH0S(7,  BPREF_E, MM_O);
    PH0S(8,  BPREF_O, MM_E);
    PH0S(9,  BPREF_E, MM_O);
    PH0S(10, BPREF_O, MM_E);
    PH0S(11, BPREF_E, MM_O);
    PH0S(12, BPREF_O, MM_E);
    // phases 13,14: no stage; VMC(4)
    RD_A(13); BPREF_E(14 * 32); VMC(4); LGKM0(); SB0(); MM_O(); BAR();
    RD_A(14); BPREF_O(15 * 32); VMC(4); LGKM0(); SB0(); MM_E(); BAR();
    // phase 15: prefetch next tile's slot 0; last barrier of the kernel loop
    RD_A(15); BPREF_E(131072); VMC(4); LGKM0(); SB0(); MM_O(); BAR();
    FOLD(); ACC_ZERO();
#pragma unroll
    for (int nt = 0; nt < 4; ++nt) bvc[nt] = biasLds[256 + wc * 64 + nt * 16 + r];
    bT0 += 131072; bT1 += 131072; bT2 += 131072; bT3 += 131072;
#undef PH0S

    // ---- tiles 1..7: stage-free, BARRIER-FREE (LDS read-only) ----
    // phase s: RD_A(s) | BPREF(s+1 or next tile) | VMC(4) | LGKM0 | MM
#define PHS(s, PREF, MM_) do {                                                  \
    RD_A(s); PREF((s + 1) * 32);                                                \
    VMC(4); LGKM0(); SB0(); MM_();                                              \
} while (0)
#pragma unroll 1
    for (int t = 1; t < 7; ++t) {
        PHS(0,  BPREF_O, MM_E);
        PHS(1,  BPREF_E, MM_O);
        PHS(2,  BPREF_O, MM_E);
        PHS(3,  BPREF_E, MM_O);
        PHS(4,  BPREF_O, MM_E);
        PHS(5,  BPREF_E, MM_O);
        PHS(6,  BPREF_O, MM_E);
        PHS(7,  BPREF_E, MM_O);
        PHS(8,  BPREF_O, MM_E);
        PHS(9,  BPREF_E, MM_O);
        PHS(10, BPREF_O, MM_E);
        PHS(11, BPREF_E, MM_O);
        PHS(12, BPREF_O, MM_E);
        PHS(13, BPREF_E, MM_O);
        PHS(14, BPREF_O, MM_E);
        // s=15: prefetch next tile slot 0 (into E)
        RD_A(15); BPREF_E(131072); VMC(4); LGKM0(); SB0(); MM_O();
        FOLD(); ACC_ZERO();
#pragma unroll
        for (int nt = 0; nt < 4; ++nt)
            bvc[nt] = biasLds[(t + 1) * 256 + wc * 64 + nt * 16 + r];
        bT0 += 131072; bT1 += 131072; bT2 += 131072; bT3 += 131072;
    }
    // ---- tile 7 (drain) ----
    PHS(0,  BPREF_O, MM_E);
    PHS(1,  BPREF_E, MM_O);
    PHS(2,  BPREF_O, MM_E);
    PHS(3,  BPREF_E, MM_O);
    PHS(4,  BPREF_O, MM_E);
    PHS(5,  BPREF_E, MM_O);
    PHS(6,  BPREF_O, MM_E);
    PHS(7,  BPREF_E, MM_O);
    PHS(8,  BPREF_O, MM_E);
    PHS(9,  BPREF_E, MM_O);
    PHS(10, BPREF_O, MM_E);
    PHS(11, BPREF_E, MM_O);
    PHS(12, BPREF_O, MM_E);
    PHS(13, BPREF_E, MM_O);
    PHS(14, BPREF_O, MM_E);
    RD_A(15); VMC(0); LGKM0(); SB0(); MM_O();
    FOLD();
#undef PHS

#undef STAGE_A
#undef RD_A
#undef BPREF_E
#undef BPREF_O
#undef MM_E
#undef MM_O
#undef BAR
#undef SB0
#undef LGKM0
#undef VMC
#undef FOLD
#undef ACC_ZERO

    // Epilogue: 16-lane r-reduce, cross-wc LDS reduce, direct out write.
    __syncthreads();
    float* smax = (float*)lds;   // 128 rows x 4 wc = 2 KB (A region is dead)
#pragma unroll
    for (int mt = 0; mt < 4; ++mt) {
#pragma unroll
        for (int rg = 0; rg < 4; ++rg) {
            float v = mx[mt][rg];
#pragma unroll
            for (int off = 1; off < 16; off <<= 1)
                v = fmaxf(v, __shfl_xor(v, off));
            if (r == 0) smax[(wr * 64 + mt * 16 + q * 4 + rg) * 4 + wc] = v;
        }
    }
    __syncthreads();
    if (tid < 128) {
        const float* p = smax + tid * 4;
        out[blockM + tid] = fmaxf(fmaxf(p[0], p[1]), fmaxf(p[2], p[3]));
    }
}

// ---------------------------------------------------------------------------
extern "C" void kernel_launch(void* const* d_in, const int* in_sizes, int n_in,
                              void* d_out, int out_size, void* d_ws, size_t ws_size,
                              hipStream_t stream) {
    const float* x   = (const float*)d_in[0];
    const float* l1w = (const float*)d_in[1];
    const float* l1b = (const float*)d_in[2];
    const float* w2  = (const float*)d_in[3];
    const float* b2  = (const float*)d_in[4];
    float* out = (float*)d_out;

    char* ws = (char*)d_ws;
    unsigned short* w1t = (unsigned short*)(ws);                 //  1 MB  w1^T bf16 [512,1024]
    unsigned short* w2b = (unsigned short*)(ws + 1048576);       //  4 MB  w2 bf16 [2048,1024]
    unsigned short* Wb  = (unsigned short*)(ws + 5242880);       //  2 MB  W bf16 [2048,512]
    float* bp           = (float*)(ws + 7340032);                //  8 KB  b' fp32 [2048]
    unsigned short* xb  = (unsigned short*)(ws + 7348224);       // 32 MB  x bf16 [32768,512]

    // 1) fused pre-work: w1 transpose + w2 cvt(+bgemv) + x cvt
    prep_kernel<<<6656, 256, 0, stream>>>(
        l1w, (const float4*)w2, (const float4*)x, l1b, b2,
        w1t, (ushort4*)w2b, (ushort4*)xb, bp);

    // 2) W = w2b @ w1t^T  [2048, 512]
    gemmW_kernel<<<dim3(DIN / 64, DOUT / 64), 256, 0, stream>>>(w2b, w1t, Wb);

    // 3) scores = xb @ W^T + b', fused row-max, direct out (A-resident, B from L2)
    gemmS_kernel<<<256, 512, 0, stream>>>(xb, Wb, bp, out);
}

// Round 9
// 235.608 us; speedup vs baseline: 1.0171x; 1.0171x over previous
//
#include <hip/hip_runtime.h>
#include <hip/hip_bf16.h>
#include <stdint.h>

// Problem sizes (compile-time)
static constexpr int BATCH = 32768;
static constexpr int DIN   = 512;
static constexpr int DHID  = 1024;
static constexpr int DOUT  = 2048;

typedef __bf16 bf16x8 __attribute__((ext_vector_type(8)));
typedef float  f32x4  __attribute__((ext_vector_type(4)));

// fp32 -> bf16 round-to-nearest-even
__device__ __forceinline__ unsigned short f2bf(float f) {
    unsigned int u = __float_as_uint(f);
    u += 0x7FFFu + ((u >> 16) & 1u);
    return (unsigned short)(u >> 16);
}

// async global->LDS, 16B per lane. LDS dest = WAVE-uniform base + 16*(lane&63).
__device__ __forceinline__ void gload_lds16(const void* g, void* l) {
    __builtin_amdgcn_global_load_lds((__attribute__((address_space(1))) void*)g,
                                     (__attribute__((address_space(3))) void*)l,
                                     16, 0, 0);
}

// ===========================================================================
// scores = x @ W^T + b' (algebraic fusion; absmax 0.03125 measured)
// r23 = r22 (B direct from L2, A LDS-resident) + DEEP PIPELINE.
// r22 failed latency-bound (MfmaUtil 21%, VALU 8.7%, VGPR only 92): B had
// 1-phase prefetch slack vs hot-L2 latency, all CUs/XCD hitting the SAME W
// lines. Fixes (using the 160 spare regs):
//  - B 4-deep register prefetch (sets s&3; refill after consume) ~2600cyc slack
//  - A-frag E/O dbuf: RD_A(s+1) at phase s, lgkmcnt(4) retires older set
//  - N-walk start staggered per block (t0 = j&7): XCD's 32 blocks spread
//    over 8 W regions -> no L2 slice hotspot
// Ledger (derived, phase-exact):
//  prologue: B(0..3)+A(0,1,2) issued, VMC(0), BAR, RD_A(set0,slot0)
//  tile0 p0..14: VMC(4)  (queue alternates {A(p+1),B(p+2),A(p+2),B(p+3)}=10
//      or {B(p+3),A(p+3),B(p+4)}=9; retires A(p+1)/A(p+2)/B(p+2))
//  tile0 p15 & tiles1..6: VMC(8) (queue B(s+1..s+3)=12, retires B(s+1))
//  tile7: p0..12 VMC(8); p13 VMC(4); p14 VMC(0); p15 none
//  lgkmcnt(4) every phase retires prior RD_A set (+boundary bias reads)
// Tiles 1..7 barrier-free (LDS A read-only). Block = 128 rows x all 2048
// cols -> direct out write (no reduce kernel).
// ===========================================================================

// ---------------------------------------------------------------------------
// prep: one dispatch, region-decoded by blockIdx.x (unchanged)
// ---------------------------------------------------------------------------
__global__ __launch_bounds__(256) void prep_kernel(
    const float* __restrict__ w1, const float4* __restrict__ w2f,
    const float4* __restrict__ xf, const float* __restrict__ b1,
    const float* __restrict__ b2,
    unsigned short* __restrict__ w1t, ushort4* __restrict__ w2b,
    ushort4* __restrict__ xb, float* __restrict__ bp) {
    const int blk = blockIdx.x;
    const int t   = threadIdx.x;
    if (blk < 512) {
        __shared__ float tile[32][33];
        const int tileI = blk & 15;
        const int tileH = blk >> 4;
        const int iBase = tileI * 32, hBase = tileH * 32;
        const int col = t & 31, rowq = t >> 5;
#pragma unroll
        for (int p = 0; p < 4; ++p) {
            const int row = p * 8 + rowq;
            tile[row][col] = w1[(size_t)(hBase + row) * DIN + iBase + col];
        }
        __syncthreads();
#pragma unroll
        for (int p = 0; p < 4; ++p) {
            const int row = p * 8 + rowq;
            w1t[(size_t)(iBase + row) * DHID + hBase + col] = f2bf(tile[col][row]);
        }
    } else if (blk < 2560) {
        __shared__ float wsum[4];
        const int o = blk - 512;
        const size_t g = (size_t)o * 256 + t;
        float4 v = w2f[g];
        ushort4 ob;
        ob.x = f2bf(v.x); ob.y = f2bf(v.y); ob.z = f2bf(v.z); ob.w = f2bf(v.w);
        w2b[g] = ob;
        float4 bv = ((const float4*)b1)[t];
        float s = v.x * bv.x + v.y * bv.y + v.z * bv.z + v.w * bv.w;
#pragma unroll
        for (int off = 1; off < 64; off <<= 1) s += __shfl_xor(s, off);
        if ((t & 63) == 0) wsum[t >> 6] = s;
        __syncthreads();
        if (t == 0) bp[o] = wsum[0] + wsum[1] + wsum[2] + wsum[3] + b2[o];
    } else {
        const size_t base = (size_t)(blk - 2560) * 1024 + t;
#pragma unroll
        for (int i = 0; i < 4; ++i) {
            float4 v = xf[base + i * 256];
            ushort4 o;
            o.x = f2bf(v.x); o.y = f2bf(v.y); o.z = f2bf(v.z); o.w = f2bf(v.w);
            xb[base + i * 256] = o;
        }
    }
}

// ---------------------------------------------------------------------------
// gemmW: W[o,i] = sum_h w2b[o,h] * w1t[i,h]. (unchanged)
// ---------------------------------------------------------------------------
__global__ __launch_bounds__(256) void gemmW_kernel(
    const unsigned short* __restrict__ A,
    const unsigned short* __restrict__ Bw,
    unsigned short* __restrict__ W) {
    constexpr int K = DHID;
    __shared__ __align__(16) unsigned short sA[64 * 128];
    __shared__ __align__(16) unsigned short sB[64 * 128];

    const int tid  = threadIdx.x;
    const int lane = tid & 63;
    const int wid  = tid >> 6;
    const int wr = wid >> 1, wc = wid & 1;
    const int r = lane & 15, q = lane >> 4;
    const int blockN = blockIdx.x * 64;
    const int blockM = blockIdx.y * 64;

    const int chKey = (tid & 15) ^ ((tid >> 4) & 15);
    const size_t aBase = (size_t)(blockM + (tid >> 4)) * K + chKey * 8;
    const size_t bBase = (size_t)(blockN + (tid >> 4)) * K + chKey * 8;

    f32x4 acc[2][2];
#pragma unroll
    for (int mt = 0; mt < 2; ++mt)
#pragma unroll
        for (int nt = 0; nt < 2; ++nt) { f32x4 z = {0.f, 0.f, 0.f, 0.f}; acc[mt][nt] = z; }

    for (int k0 = 0; k0 < K; k0 += 128) {
#pragma unroll
        for (int j = 0; j < 4; ++j) {
            gload_lds16(A  + aBase + (size_t)j * 16 * K + k0, sA + j * 2048 + wid * 512);
            gload_lds16(Bw + bBase + (size_t)j * 16 * K + k0, sB + j * 2048 + wid * 512);
        }
        __syncthreads();
#pragma unroll
        for (int ks = 0; ks < 4; ++ks) {
            const int ch = ((ks << 2) + q) ^ r;
            bf16x8 af[2], bf[2];
#pragma unroll
            for (int mt = 0; mt < 2; ++mt) af[mt] = *(const bf16x8*)&sA[(wr * 32 + mt * 16 + r) * 128 + ch * 8];
#pragma unroll
            for (int nt = 0; nt < 2; ++nt) bf[nt] = *(const bf16x8*)&sB[(wc * 32 + nt * 16 + r) * 128 + ch * 8];
#pragma unroll
            for (int mt = 0; mt < 2; ++mt)
#pragma unroll
                for (int nt = 0; nt < 2; ++nt)
                    acc[mt][nt] = __builtin_amdgcn_mfma_f32_16x16x32_bf16(af[mt], bf[nt], acc[mt][nt], 0, 0, 0);
        }
        __syncthreads();
    }

#pragma unroll
    for (int mt = 0; mt < 2; ++mt) {
        const int row0 = blockM + wr * 32 + mt * 16 + q * 4;
#pragma unroll
        for (int nt = 0; nt < 2; ++nt) {
            const int col = blockN + wc * 32 + nt * 16 + r;
#pragma unroll
            for (int reg = 0; reg < 4; ++reg)
                W[(size_t)(row0 + reg) * DIN + col] = f2bf(acc[mt][nt][reg]);
        }
    }
}

// ---------------------------------------------------------------------------
// gemmS r23: 256 blocks x 512 thr (8 waves = 2M x 4N), BM=128.
// A LDS-resident (16 K32-slots x 8KB at s*4096 sh; bias 8KB at 65536). 136KB.
// Walks 8 N-tiles of 256 cols, start staggered: memory tile (t0+w)&7.
// B direct L2->reg, 4-deep sets (set = slot&3); A-frag E/O dbuf (set=slot&1).
// ---------------------------------------------------------------------------
__global__ __launch_bounds__(512, 2) void gemmS_kernel(
    const unsigned short* __restrict__ A,   // xb bf16 [BATCH, DIN]
    const unsigned short* __restrict__ Bw,  // W bf16 [2048, 512]
    const float* __restrict__ bp,           // b' [DOUT]
    float* __restrict__ out) {              // [BATCH]
    __shared__ __align__(16) unsigned short lds[69632];  // 136 KB

    const int tid  = threadIdx.x;            // 0..511
    const int lane = tid & 63;
    const int wid  = tid >> 6;               // 0..7
    const int wr   = wid >> 2;               // 0..1 (M half)
    const int wc   = wid & 3;                // 0..3 (N quarter)
    const int r    = lane & 15, q = lane >> 4;

    // 256 blocks = 8 xcd x 32; block owns 128 rows, all 2048 cols.
    const int b    = blockIdx.x;
    const int xcd  = b & 7;
    const int j    = b >> 3;                 // 0..31
    const int blockM = (xcd * 32 + j) * 128;
    const int t0   = j & 7;                  // staggered N-walk start

    // A staging (pre-swizzled global source); 1 gload per slot (8KB).
    const int sRow = tid >> 2;               // 0..127
    const int swz  = (tid & 3) ^ ((tid >> 3) & 3);
    const unsigned short* aSrc = A + (size_t)(blockM + sRow) * DIN + swz * 8;
    float* biasLds = (float*)(lds + 65536);

#define STAGE_A(s) \
    gload_lds16(aSrc + (s) * 32, lds + (s) * 4096 + wid * 512)

    // A fragment read base (swizzled chunk)
    const int fOff = (q ^ ((r >> 1) & 3)) * 8;
    const unsigned short* ldsAf = lds + (wr * 64 + r) * 32 + fOff;

    // B per-lane base: row = wc*64 + nt*16 + r (nt adds 8192 sh), col-octet q.
    const unsigned short* bLane = Bw + (size_t)(wc * 64 + r) * DIN + q * 8;
    int tCur = t0, tNxt = (t0 + 1) & 7;
    const unsigned short* bTc = bLane + (size_t)tCur * 131072;
    const unsigned short* bTn = bLane + (size_t)tNxt * 131072;

    f32x4 acc[4][4];
#pragma unroll
    for (int mt = 0; mt < 4; ++mt)
#pragma unroll
        for (int nt = 0; nt < 4; ++nt) { f32x4 z = {0.f, 0.f, 0.f, 0.f}; acc[mt][nt] = z; }
    float mx[4][4];
#pragma unroll
    for (int mt = 0; mt < 4; ++mt)
#pragma unroll
        for (int rg = 0; rg < 4; ++rg) mx[mt][rg] = -INFINITY;
    bf16x8 af[2][4];      // E/O A-frag sets
    bf16x8 bfr[4][4];     // 4-deep B sets
    float bvc[4];

// All reg-array indices below are macro LITERALS (rule #20: static indexing).
#define RD_A(SET, s) do {                                                       \
    const unsigned short* pa_ = ldsAf + (s) * 4096;                             \
    af[SET][0] = *(const bf16x8*)(pa_);                                         \
    af[SET][1] = *(const bf16x8*)(pa_ + 512);                                   \
    af[SET][2] = *(const bf16x8*)(pa_ + 1024);                                  \
    af[SET][3] = *(const bf16x8*)(pa_ + 1536);                                  \
} while (0)
#define BPREF(SET, BP, k) do {                                                  \
    bfr[SET][0] = *(const bf16x8*)((BP) + (k) * 32);                            \
    bfr[SET][1] = *(const bf16x8*)((BP) + 8192 + (k) * 32);                     \
    bfr[SET][2] = *(const bf16x8*)((BP) + 16384 + (k) * 32);                    \
    bfr[SET][3] = *(const bf16x8*)((BP) + 24576 + (k) * 32);                    \
} while (0)
#define MM(AF, BS) do {                                                         \
    __builtin_amdgcn_s_setprio(1);                                              \
    _Pragma("unroll") for (int m_ = 0; m_ < 4; ++m_)                            \
    _Pragma("unroll") for (int n_ = 0; n_ < 4; ++n_)                            \
        acc[m_][n_] = __builtin_amdgcn_mfma_f32_16x16x32_bf16(                  \
            af[AF][m_], bfr[BS][n_], acc[m_][n_], 0, 0, 0);                     \
    __builtin_amdgcn_s_setprio(0);                                              \
} while (0)
#define BAR()   __builtin_amdgcn_s_barrier()
#define SB0()   __builtin_amdgcn_sched_barrier(0)
#define LGKM0() asm volatile("s_waitcnt lgkmcnt(0)" ::: "memory")
#define LGKM4() asm volatile("s_waitcnt lgkmcnt(4)" ::: "memory")
#define VMC(n)  asm volatile("s_waitcnt vmcnt(" #n ")" ::: "memory")

#define FOLD() do {                                                             \
    _Pragma("unroll") for (int mt_ = 0; mt_ < 4; ++mt_)                         \
    _Pragma("unroll") for (int rg_ = 0; rg_ < 4; ++rg_) {                       \
        float v_ = fmaxf(fmaxf(acc[mt_][0][rg_] + bvc[0],                       \
                               acc[mt_][1][rg_] + bvc[1]),                      \
                         fmaxf(acc[mt_][2][rg_] + bvc[2],                       \
                               acc[mt_][3][rg_] + bvc[3]));                     \
        mx[mt_][rg_] = fmaxf(mx[mt_][rg_], v_);                                 \
    }                                                                           \
} while (0)
#define ACC_ZERO() do {                                                         \
    _Pragma("unroll") for (int mt_ = 0; mt_ < 4; ++mt_)                         \
    _Pragma("unroll") for (int nt_ = 0; nt_ < 4; ++nt_) {                       \
        f32x4 z_ = {0.f, 0.f, 0.f, 0.f}; acc[mt_][nt_] = z_;                    \
    }                                                                           \
} while (0)

    // ---- Prologue ----
    {
        float4 bb = ((const float4*)bp)[tid];      // 8 KB = all of b'
        ((float4*)biasLds)[tid] = bb;
    }
    BPREF(0, bTc, 0); BPREF(1, bTc, 1); BPREF(2, bTc, 2); BPREF(3, bTc, 3);
    STAGE_A(0); STAGE_A(1); STAGE_A(2);
    LGKM0(); VMC(0);
    BAR();
    RD_A(0, 0);
#pragma unroll
    for (int nt = 0; nt < 4; ++nt) bvc[nt] = biasLds[tCur * 256 + wc * 64 + nt * 16 + r];

    // Tile boundary tail (tiles 0..6): fold, advance walk, reload bias.
#define TILE_TAIL() do {                                                        \
    FOLD(); ACC_ZERO();                                                         \
    tCur = tNxt; tNxt = (tNxt + 1) & 7;                                         \
    bTc = bTn; bTn = bLane + (size_t)tNxt * 131072;                             \
    _Pragma("unroll") for (int nt_ = 0; nt_ < 4; ++nt_)                         \
        bvc[nt_] = biasLds[tCur * 256 + wc * 64 + nt_ * 16 + r];                \
} while (0)

    // ---- tile 0 (A staging + barriers; VMC(4) p0..14, VMC(8) p15) ----
#define PT0(p, VN, STG, PREF) do {                                              \
    RD_A(((p) + 1) & 1, ((p) + 1) & 15);                                        \
    VMC(VN); LGKM4(); SB0();                                                    \
    MM((p) & 1, (p) & 3);                                                       \
    STG; PREF;                                                                  \
    BAR(); SB0();                                                               \
} while (0)
    PT0(0,  4, STAGE_A(3),  BPREF(0, bTc, 4));
    PT0(1,  4, STAGE_A(4),  BPREF(1, bTc, 5));
    PT0(2,  4, STAGE_A(5),  BPREF(2, bTc, 6));
    PT0(3,  4, STAGE_A(6),  BPREF(3, bTc, 7));
    PT0(4,  4, STAGE_A(7),  BPREF(0, bTc, 8));
    PT0(5,  4, STAGE_A(8),  BPREF(1, bTc, 9));
    PT0(6,  4, STAGE_A(9),  BPREF(2, bTc, 10));
    PT0(7,  4, STAGE_A(10), BPREF(3, bTc, 11));
    PT0(8,  4, STAGE_A(11), BPREF(0, bTc, 12));
    PT0(9,  4, STAGE_A(12), BPREF(1, bTc, 13));
    PT0(10, 4, STAGE_A(13), BPREF(2, bTc, 14));
    PT0(11, 4, STAGE_A(14), BPREF(3, bTc, 15));
    PT0(12, 4, STAGE_A(15), BPREF(0, bTn, 0));
    PT0(13, 4, (void)0,     BPREF(1, bTn, 1));
    PT0(14, 4, (void)0,     BPREF(2, bTn, 2));
    PT0(15, 8, (void)0,     BPREF(3, bTn, 3));
    TILE_TAIL();
#undef PT0

    // ---- tiles 1..6 (barrier-free, VMC(8) all phases) ----
#define PS(p, PREF) do {                                                        \
    RD_A(((p) + 1) & 1, ((p) + 1) & 15);                                        \
    VMC(8); LGKM4(); SB0();                                                     \
    MM((p) & 1, (p) & 3);                                                       \
    PREF;                                                                       \
} while (0)
#pragma unroll 1
    for (int w = 1; w < 7; ++w) {
        PS(0,  BPREF(0, bTc, 4));
        PS(1,  BPREF(1, bTc, 5));
        PS(2,  BPREF(2, bTc, 6));
        PS(3,  BPREF(3, bTc, 7));
        PS(4,  BPREF(0, bTc, 8));
        PS(5,  BPREF(1, bTc, 9));
        PS(6,  BPREF(2, bTc, 10));
        PS(7,  BPREF(3, bTc, 11));
        PS(8,  BPREF(0, bTc, 12));
        PS(9,  BPREF(1, bTc, 13));
        PS(10, BPREF(2, bTc, 14));
        PS(11, BPREF(3, bTc, 15));
        PS(12, BPREF(0, bTn, 0));
        PS(13, BPREF(1, bTn, 1));
        PS(14, BPREF(2, bTn, 2));
        PS(15, BPREF(3, bTn, 3));
        TILE_TAIL();
    }

    // ---- tile 7 (drain) ----
    PS(0,  BPREF(0, bTc, 4));
    PS(1,  BPREF(1, bTc, 5));
    PS(2,  BPREF(2, bTc, 6));
    PS(3,  BPREF(3, bTc, 7));
    PS(4,  BPREF(0, bTc, 8));
    PS(5,  BPREF(1, bTc, 9));
    PS(6,  BPREF(2, bTc, 10));
    PS(7,  BPREF(3, bTc, 11));
    PS(8,  BPREF(0, bTc, 12));
    PS(9,  BPREF(1, bTc, 13));
    PS(10, BPREF(2, bTc, 14));
    PS(11, BPREF(3, bTc, 15));
    // p12..15: no prefetch; VMC ramp 8/4/0/-
    RD_A(1, 13); VMC(8); LGKM4(); SB0(); MM(0, 0);
    RD_A(0, 14); VMC(4); LGKM4(); SB0(); MM(1, 1);
    RD_A(1, 15); VMC(0); LGKM4(); SB0(); MM(0, 2);
    RD_A(0, 0);          LGKM4(); SB0(); MM(1, 3);
    FOLD();
#undef PS

#undef STAGE_A
#undef RD_A
#undef BPREF
#undef MM
#undef BAR
#undef SB0
#undef LGKM0
#undef LGKM4
#undef VMC
#undef FOLD
#undef ACC_ZERO
#undef TILE_TAIL

    // Epilogue: 16-lane r-reduce, cross-wc LDS reduce, direct out write.
    __syncthreads();
    float* smax = (float*)lds;   // 128 rows x 4 wc = 2 KB (A region is dead)
#pragma unroll
    for (int mt = 0; mt < 4; ++mt) {
#pragma unroll
        for (int rg = 0; rg < 4; ++rg) {
            float v = mx[mt][rg];
#pragma unroll
            for (int off = 1; off < 16; off <<= 1)
                v = fmaxf(v, __shfl_xor(v, off));
            if (r == 0) smax[(wr * 64 + mt * 16 + q * 4 + rg) * 4 + wc] = v;
        }
    }
    __syncthreads();
    if (tid < 128) {
        const float* p = smax + tid * 4;
        out[blockM + tid] = fmaxf(fmaxf(p[0], p[1]), fmaxf(p[2], p[3]));
    }
}

// ---------------------------------------------------------------------------
extern "C" void kernel_launch(void* const* d_in, const int* in_sizes, int n_in,
                              void* d_out, int out_size, void* d_ws, size_t ws_size,
                              hipStream_t stream) {
    const float* x   = (const float*)d_in[0];
    const float* l1w = (const float*)d_in[1];
    const float* l1b = (const float*)d_in[2];
    const float* w2  = (const float*)d_in[3];
    const float* b2  = (const float*)d_in[4];
    float* out = (float*)d_out;

    char* ws = (char*)d_ws;
    unsigned short* w1t = (unsigned short*)(ws);                 //  1 MB  w1^T bf16 [512,1024]
    unsigned short* w2b = (unsigned short*)(ws + 1048576);       //  4 MB  w2 bf16 [2048,1024]
    unsigned short* Wb  = (unsigned short*)(ws + 5242880);       //  2 MB  W bf16 [2048,512]
    float* bp           = (float*)(ws + 7340032);                //  8 KB  b' fp32 [2048]
    unsigned short* xb  = (unsigned short*)(ws + 7348224);       // 32 MB  x bf16 [32768,512]

    // 1) fused pre-work: w1 transpose + w2 cvt(+bgemv) + x cvt
    prep_kernel<<<6656, 256, 0, stream>>>(
        l1w, (const float4*)w2, (const float4*)x, l1b, b2,
        w1t, (ushort4*)w2b, (ushort4*)xb, bp);

    // 2) W = w2b @ w1t^T  [2048, 512]
    gemmW_kernel<<<dim3(DIN / 64, DOUT / 64), 256, 0, stream>>>(w2b, w1t, Wb);

    // 3) scores = xb @ W^T + b', fused row-max, direct out (deep pipeline)
    gemmS_kernel<<<256, 512, 0, stream>>>(xb, Wb, bp, out);
}